// Round 12
// baseline (1862.246 us; speedup 1.0000x reference)
//
#include <hip/hip_runtime.h>
#include <hip/hip_bf16.h>

typedef _Float16 half8 __attribute__((ext_vector_type(8)));
typedef _Float16 half4 __attribute__((ext_vector_type(4)));
typedef float    floatx4 __attribute__((ext_vector_type(4)));

#define B_TOT 4096
#define L_SEQ 2048
#define H_DIM 256
#define FUT   128
#define T_TOT (L_SEQ + FUT)   /* 2176 */
#define ROWS  16              /* batch rows per block, 256 blocks = 1/CU */
#define CHUNK 128             /* x prefetch chunk (steps) */

// tanh(p) = 1 - 2/(e^{2p}+1); exp2 over/underflow saturate to exact +-1.
__device__ __forceinline__ float tanh_fast(float p) {
    float e = __builtin_amdgcn_exp2f(p * 2.885390082f);     // e^(2p)
    return __builtin_fmaf(-2.0f, __builtin_amdgcn_rcpf(e + 1.0f), 1.0f);
}

// R8 base (8 waves x 2 N-tiles, swapped-operand MFMA C=W(A)@h^T(B), XOR-
// swizzled fp16 h double-buffer, LDS out-ring) with DISTRIBUTED LIN:
// at epilogue time each wave holds its own 32 neurons' h values (tv), so its
// lin contribution is an 8-FMA register dot + shfl_xor(16,32) + one 16-lane
// LDS atomicAdd into the out-ring (~60 cyc, symmetric).  This removes R8's
// wave-0 post-barrier lin tile (the ~155 cyc/step barrier straggler), writes
// out[t] at step t+1 (one step earlier), which turns the future-phase
// feedback into a plain LDS read at step start -> future body == main body
// (no all-wave lin MFMAs), and the last output falls out of the loop.
// No K-skew, no setprio (R11: both regressed).
__global__ __launch_bounds__(512, 2) void rnn_seq_kernel(
    const float* __restrict__ x,      // [B, L]
    const float* __restrict__ W_ih,   // [H]
    const float* __restrict__ b_ih,   // [H]
    const float* __restrict__ W_hh,   // [H, H]
    const float* __restrict__ b_hh,   // [H]
    const float* __restrict__ W_lin,  // [H]
    const float* __restrict__ b_lin,  // [1]
    float* __restrict__ out)          // [B, T_TOT]
{
    __shared__ __align__(16) unsigned char hbuf[2][ROWS * H_DIM * 2]; // fp16 dbuf
    __shared__ __align__(16) float xbuf[CHUNK * 17];                  // [t_local][row]
    __shared__ __align__(16) float obuf[64][17];                      // out ring (t&63)

    const int tid  = threadIdx.x;
    const int l    = tid & 63;
    const int w    = tid >> 6;       // wave 0..7
    const int ln15 = l & 15;
    const int lg   = l >> 4;         // 0..3
    const int b0   = blockIdx.x * ROWS;

    // ---- loop-invariant register state ----
    half8 wf[2][8];                   // W_hh A-frags: 2 N-tiles per wave
    #pragma unroll
    for (int i = 0; i < 2; ++i) {
        const int n = (2 * w + i) * 16 + ln15;
        #pragma unroll
        for (int kk = 0; kk < 8; ++kk) {
            const float* p = W_hh + n * H_DIM + kk * 32 + lg * 8;
            half8 v;
            #pragma unroll
            for (int j = 0; j < 8; ++j) v[j] = (_Float16)p[j];
            wf[i][kk] = v;
        }
    }
    floatx4 wih4[2], bia4[2];
    float wlp[2][4];                  // W_lin for this lane's own neurons
    #pragma unroll
    for (int i = 0; i < 2; ++i) {
        const int n0 = (2 * w + i) * 16 + lg * 4;
        #pragma unroll
        for (int r = 0; r < 4; ++r) {
            wih4[i][r] = W_ih[n0 + r];
            bia4[i][r] = b_ih[n0 + r] + b_hh[n0 + r];
            wlp[i][r]  = W_lin[n0 + r];
        }
    }
    const float blin = b_lin[0];

    // LDS byte offsets (XOR swizzle bits 4-6 keyed by row&7)
    int aoff[8];
    #pragma unroll
    for (int kk = 0; kk < 8; ++kk)
        aoff[kk] = (ln15 * 512 + kk * 64 + lg * 16) ^ ((ln15 & 7) << 4);
    int woff2[2];
    #pragma unroll
    for (int i = 0; i < 2; ++i)
        woff2[i] = (ln15 * 512 + (2 * w + i) * 32 + lg * 8) ^ ((ln15 & 7) << 4);

    // init: h0 = 0, obuf zeroed
    *(floatx4*)(hbuf[0] + tid * 16) = floatx4{0.f, 0.f, 0.f, 0.f};
    #pragma unroll
    for (int i = 0; i < 3; ++i) {
        const int idx = i * 512 + tid;
        if (idx < 64 * 17) ((float*)obuf)[idx] = 0.f;
    }
    __syncthreads();

    int cur = 0;

    // Flush: at ((s-1)&31)==1, entries [s-34, s-3] are complete (entry t is
    // written pre-barrier at step t+1) -> coalesced store + re-zero slots.
#define FLUSH_BLOCK(s_)                                                       \
    do {                                                                      \
        const int tb = (s_) - 34;                                             \
        const int rr = tid >> 5, tt = tid & 31;                               \
        const int slot = (tb + tt) & 63;                                      \
        const float v_ = obuf[slot][rr];                                      \
        out[(size_t)(b0 + rr) * T_TOT + tb + tt] = v_ + blin;                 \
        obuf[slot][rr] = 0.f;                                                 \
    } while (0)

    // ============================ main phase ============================
    for (int s = 1; s <= L_SEQ; ++s) {
        if (s >= 34 && ((s - 1) & 31) == 1) FLUSH_BLOCK(s);
        if (((s - 1) & (CHUNK - 1)) == 0) {           // x chunk prefetch
            #pragma unroll
            for (int jj = 0; jj < 4; ++jj) {
                const int idx = jj * 512 + tid;
                const int rr = idx >> 7, tl = idx & 127;
                xbuf[tl * 17 + rr] = x[(size_t)(b0 + rr) * L_SEQ + (s - 1) + tl];
            }
            __syncthreads();
        }

        half8 a[8];                                    // B-frags of h_{s-1}
        #pragma unroll
        for (int kk = 0; kk < 8; ++kk)
            a[kk] = *(const half8*)(hbuf[cur] + aoff[kk]);
        const float xm = xbuf[((s - 1) & (CHUNK - 1)) * 17 + ln15];

        // 2 chains per tile; chain0 init = fma(x, W_ih, bias)
        floatx4 acc[2][2];
        #pragma unroll
        for (int i = 0; i < 2; ++i) {
            #pragma unroll
            for (int r = 0; r < 4; ++r)
                acc[i][0][r] = __builtin_fmaf(xm, wih4[i][r], bia4[i][r]);
            acc[i][1] = floatx4{0, 0, 0, 0};
        }
        #pragma unroll
        for (int kk = 0; kk < 8; ++kk) {
            acc[0][kk & 1] = __builtin_amdgcn_mfma_f32_16x16x32_f16(wf[0][kk], a[kk], acc[0][kk & 1], 0, 0, 0);
            acc[1][kk & 1] = __builtin_amdgcn_mfma_f32_16x16x32_f16(wf[1][kk], a[kk], acc[1][kk & 1], 0, 0, 0);
        }
        // epilogue: tanh + packed h-write + distributed lin partial
        float tv[2][4];
        #pragma unroll
        for (int i = 0; i < 2; ++i) {
            const floatx4 av = acc[i][0] + acc[i][1];
            half4 hv;
            #pragma unroll
            for (int r = 0; r < 4; ++r) {
                tv[i][r] = tanh_fast(av[r]);
                hv[r] = (_Float16)tv[i][r];
            }
            *(half4*)(hbuf[cur ^ 1] + woff2[i]) = hv;
        }
        float part = 0.f;
        #pragma unroll
        for (int i = 0; i < 2; ++i)
            #pragma unroll
            for (int r = 0; r < 4; ++r)
                part = __builtin_fmaf(tv[i][r], wlp[i][r], part);
        part += __shfl_xor(part, 16);
        part += __shfl_xor(part, 32);
        if (l < 16) atomicAdd(&obuf[(s - 1) & 63][l], part);  // out[s-1] partial

        __syncthreads();
        cur ^= 1;
    }

    // ============================ future phase ============================
    // out[s-2] was fully accumulated before the previous barrier -> the
    // feedback input is a plain LDS read; body otherwise == main body.
    for (int s = L_SEQ + 1; s <= T_TOT; ++s) {
        if (((s - 1) & 31) == 1) FLUSH_BLOCK(s);

        half8 a[8];
        #pragma unroll
        for (int kk = 0; kk < 8; ++kk)
            a[kk] = *(const half8*)(hbuf[cur] + aoff[kk]);
        const float xm = obuf[(s - 2) & 63][ln15] + blin;   // fed-back output

        floatx4 acc[2][2];
        #pragma unroll
        for (int i = 0; i < 2; ++i) {
            #pragma unroll
            for (int r = 0; r < 4; ++r)
                acc[i][0][r] = __builtin_fmaf(xm, wih4[i][r], bia4[i][r]);
            acc[i][1] = floatx4{0, 0, 0, 0};
        }
        #pragma unroll
        for (int kk = 0; kk < 8; ++kk) {
            acc[0][kk & 1] = __builtin_amdgcn_mfma_f32_16x16x32_f16(wf[0][kk], a[kk], acc[0][kk & 1], 0, 0, 0);
            acc[1][kk & 1] = __builtin_amdgcn_mfma_f32_16x16x32_f16(wf[1][kk], a[kk], acc[1][kk & 1], 0, 0, 0);
        }
        float tv[2][4];
        #pragma unroll
        for (int i = 0; i < 2; ++i) {
            const floatx4 av = acc[i][0] + acc[i][1];
            half4 hv;
            #pragma unroll
            for (int r = 0; r < 4; ++r) {
                tv[i][r] = tanh_fast(av[r]);
                hv[r] = (_Float16)tv[i][r];
            }
            *(half4*)(hbuf[cur ^ 1] + woff2[i]) = hv;
        }
        float part = 0.f;
        #pragma unroll
        for (int i = 0; i < 2; ++i)
            #pragma unroll
            for (int r = 0; r < 4; ++r)
                part = __builtin_fmaf(tv[i][r], wlp[i][r], part);
        part += __shfl_xor(part, 16);
        part += __shfl_xor(part, 32);
        if (l < 16) atomicAdd(&obuf[(s - 1) & 63][l], part);

        __syncthreads();
        cur ^= 1;
    }

    // final flush: t = 2144..2175 (entry 2175 = lin(h_2176), written at
    // s=2176 pre-barrier; loop's last __syncthreads makes all atomics visible)
    {
        const int rr = tid >> 5, tt = tid & 31;
        out[(size_t)(b0 + rr) * T_TOT + 2144 + tt] = obuf[(2144 + tt) & 63][rr] + blin;
    }
#undef FLUSH_BLOCK
}

extern "C" void kernel_launch(void* const* d_in, const int* in_sizes, int n_in,
                              void* d_out, int out_size, void* d_ws, size_t ws_size,
                              hipStream_t stream) {
    const float* x     = (const float*)d_in[0];
    const float* W_ih  = (const float*)d_in[1];
    const float* b_ih  = (const float*)d_in[2];
    const float* W_hh  = (const float*)d_in[3];
    const float* b_hh  = (const float*)d_in[4];
    const float* W_lin = (const float*)d_in[5];
    const float* b_lin = (const float*)d_in[6];
    float* out = (float*)d_out;
    rnn_seq_kernel<<<B_TOT / ROWS, 512, 0, stream>>>(x, W_ih, b_ih, W_hh, b_hh, W_lin, b_lin, out);
}

// Round 13
// 1596.309 us; speedup vs baseline: 1.1666x; 1.1666x over previous
//
#include <hip/hip_runtime.h>
#include <hip/hip_bf16.h>

typedef _Float16 half8 __attribute__((ext_vector_type(8)));
typedef _Float16 half4 __attribute__((ext_vector_type(4)));
typedef float    floatx4 __attribute__((ext_vector_type(4)));

#define B_TOT 4096
#define L_SEQ 2048
#define H_DIM 256
#define FUT   128
#define T_TOT (L_SEQ + FUT)   /* 2176 */
#define ROWS  16              /* batch rows per block, 256 blocks = 1/CU */

// tanh(p) = 1 - 2/(e^{2p}+1); exp2 over/underflow saturate to exact +-1.
__device__ __forceinline__ float tanh_fast(float p) {
    float e = __builtin_amdgcn_exp2f(p * 2.885390082f);     // e^(2p)
    return __builtin_fmaf(-2.0f, __builtin_amdgcn_rcpf(e + 1.0f), 1.0f);
}

// R8 base (best: 8 waves x 2 N-tiles, swapped-operand MFMA C=W(A)@h^T(B),
// XOR-swizzled fp16 h dbuf, post-barrier w0 lin, in-register future feedback,
// LDS out-ring) + two critical-path cuts:
//  1. x prefetched per-wave into a REGISTER one step ahead (global load
//     issued at step start, used next step): removes the xbuf chunk barriers
//     (16 of them) and one LDS read + addressing per step per wave.
//  2. Epilogue split by tile: tile0 MFMAs -> tanh0+write0 -> tile1 MFMAs ->
//     tanh1+write1.  tanh0 (trans unit) and write0 (LDS) overlap tile1's
//     MFMA issue -> barrier arrives earlier.
// R9/R11/R12 lessons: no spin-flags, no K-skew, no setprio, no pre-barrier
// shfl/atomic chains.
__global__ __launch_bounds__(512, 2) void rnn_seq_kernel(
    const float* __restrict__ x,      // [B, L]
    const float* __restrict__ W_ih,   // [H]
    const float* __restrict__ b_ih,   // [H]
    const float* __restrict__ W_hh,   // [H, H]
    const float* __restrict__ b_hh,   // [H]
    const float* __restrict__ W_lin,  // [H]
    const float* __restrict__ b_lin,  // [1]
    float* __restrict__ out)          // [B, T_TOT]
{
    __shared__ __align__(16) unsigned char hbuf[2][ROWS * H_DIM * 2]; // fp16 dbuf
    __shared__ __align__(16) float obuf2[2][32][17];                  // out ring

    const int tid  = threadIdx.x;
    const int l    = tid & 63;
    const int w    = tid >> 6;       // wave 0..7
    const int ln15 = l & 15;
    const int lg   = l >> 4;         // 0..3
    const int b0   = blockIdx.x * ROWS;

    // ---- loop-invariant register state ----
    half8 wf[2][8];                   // W_hh A-frags: 2 N-tiles per wave
    #pragma unroll
    for (int i = 0; i < 2; ++i) {
        const int n = (2 * w + i) * 16 + ln15;
        #pragma unroll
        for (int kk = 0; kk < 8; ++kk) {
            const float* p = W_hh + n * H_DIM + kk * 32 + lg * 8;
            half8 v;
            #pragma unroll
            for (int j = 0; j < 8; ++j) v[j] = (_Float16)p[j];
            wf[i][kk] = v;
        }
    }
    // W_lin A-frag in rows 0,4,8,12 -> C rows 0,4,8,12 all = lin(h):
    // al[0] valid at every lane group lg (future feedback + w0 lin).
    half8 wlf[8];
    #pragma unroll
    for (int kk = 0; kk < 8; ++kk) {
        const int kbase = kk * 32 + lg * 8;
        half8 v;
        #pragma unroll
        for (int j = 0; j < 8; ++j)
            v[j] = ((ln15 & 3) == 0) ? (_Float16)W_lin[kbase + j] : (_Float16)0.0f;
        wlf[kk] = v;
    }
    floatx4 wih4[2], bia4[2];
    #pragma unroll
    for (int i = 0; i < 2; ++i) {
        const int n0 = (2 * w + i) * 16 + lg * 4;
        #pragma unroll
        for (int r = 0; r < 4; ++r) {
            wih4[i][r] = W_ih[n0 + r];
            bia4[i][r] = b_ih[n0 + r] + b_hh[n0 + r];
        }
    }
    const float blin = b_lin[0];

    // LDS byte offsets (XOR swizzle bits 4-6 keyed by row&7)
    int aoff[8];
    #pragma unroll
    for (int kk = 0; kk < 8; ++kk)
        aoff[kk] = (ln15 * 512 + kk * 64 + lg * 16) ^ ((ln15 & 7) << 4);
    int woff2[2];
    #pragma unroll
    for (int i = 0; i < 2; ++i)
        woff2[i] = (ln15 * 512 + (2 * w + i) * 32 + lg * 8) ^ ((ln15 & 7) << 4);

    *(floatx4*)(hbuf[0] + tid * 16) = floatx4{0.f, 0.f, 0.f, 0.f};  // h0 = 0
    __syncthreads();

    int cur = 0;
    const float* xrow = x + (size_t)(b0 + ln15) * L_SEQ;
    float xr = xrow[0];               // x for step 1

    // ============================ main phase ============================
    for (int s = 1; s <= L_SEQ; ++s) {
        const int t_out = s - 2;

        // flush completed 32-block [t_out-34, t_out-3]: newest entry was
        // written >=2 barriers ago (post-barrier lin needs the margin)
        if (t_out >= 34 && (t_out & 31) == 2) {
            const int tb = t_out - 34, par = (tb >> 5) & 1;
            const int rr = tid >> 5, tt = tid & 31;
            out[(size_t)(b0 + rr) * T_TOT + tb + tt] = obuf2[par][tt][rr] + blin;
        }

        // B-frags of h_{s-1}
        half8 a[8];
        #pragma unroll
        for (int kk = 0; kk < 8; ++kk)
            a[kk] = *(const half8*)(hbuf[cur] + aoff[kk]);

        // prefetch next step's x into a register (consumed next iteration;
        // the load drains long before this step's barrier)
        const float xm = xr;
        if (s < L_SEQ) xr = xrow[s];

        // ---- tile 0: 2-chain MFMA, chain0 init = fma(x, W_ih, bias) ----
        floatx4 acc00, acc01;
        #pragma unroll
        for (int r = 0; r < 4; ++r)
            acc00[r] = __builtin_fmaf(xm, wih4[0][r], bia4[0][r]);
        acc01 = floatx4{0, 0, 0, 0};
        #pragma unroll
        for (int kk = 0; kk < 8; ++kk) {
            if (kk & 1) acc01 = __builtin_amdgcn_mfma_f32_16x16x32_f16(wf[0][kk], a[kk], acc01, 0, 0, 0);
            else        acc00 = __builtin_amdgcn_mfma_f32_16x16x32_f16(wf[0][kk], a[kk], acc00, 0, 0, 0);
        }
        {   // tanh + write tile 0 (overlaps tile 1's MFMA issue)
            const floatx4 av = acc00 + acc01;
            half4 hv;
            #pragma unroll
            for (int r = 0; r < 4; ++r) hv[r] = (_Float16)tanh_fast(av[r]);
            *(half4*)(hbuf[cur ^ 1] + woff2[0]) = hv;
        }
        // ---- tile 1 ----
        floatx4 acc10, acc11;
        #pragma unroll
        for (int r = 0; r < 4; ++r)
            acc10[r] = __builtin_fmaf(xm, wih4[1][r], bia4[1][r]);
        acc11 = floatx4{0, 0, 0, 0};
        #pragma unroll
        for (int kk = 0; kk < 8; ++kk) {
            if (kk & 1) acc11 = __builtin_amdgcn_mfma_f32_16x16x32_f16(wf[1][kk], a[kk], acc11, 0, 0, 0);
            else        acc10 = __builtin_amdgcn_mfma_f32_16x16x32_f16(wf[1][kk], a[kk], acc10, 0, 0, 0);
        }
        {
            const floatx4 av = acc10 + acc11;
            half4 hv;
            #pragma unroll
            for (int r = 0; r < 4; ++r) hv[r] = (_Float16)tanh_fast(av[r]);
            *(half4*)(hbuf[cur ^ 1] + woff2[1]) = hv;
        }
        __syncthreads();

        // lin AFTER the barrier (wave 0 only; a[] still holds h_{s-1}):
        // overlaps the other waves' next-step LDS reads.
        if (w == 0 && s >= 2) {
            floatx4 al0 = floatx4{0,0,0,0}, al1 = floatx4{0,0,0,0};
            #pragma unroll
            for (int kk = 0; kk < 8; ++kk) {
                if (kk & 1) al1 = __builtin_amdgcn_mfma_f32_16x16x32_f16(wlf[kk], a[kk], al1, 0, 0, 0);
                else        al0 = __builtin_amdgcn_mfma_f32_16x16x32_f16(wlf[kk], a[kk], al0, 0, 0, 0);
            }
            if (lg == 0)
                obuf2[(t_out >> 5) & 1][t_out & 31][ln15] = al0[0] + al1[0];
        }
        cur ^= 1;
    }

    // ============================ future phase ============================
    // feedback in-register (al[0] valid in every lane group): 1 barrier/step
    for (int s = L_SEQ + 1; s <= T_TOT; ++s) {
        const int t_out = s - 2;
        if ((t_out & 31) == 2) {                       // ring flush (same margin)
            const int tb = t_out - 34, par = (tb >> 5) & 1;
            const int rr = tid >> 5, tt = tid & 31;
            out[(size_t)(b0 + rr) * T_TOT + tb + tt] = obuf2[par][tt][rr] + blin;
        }
        half8 a[8];
        #pragma unroll
        for (int kk = 0; kk < 8; ++kk)
            a[kk] = *(const half8*)(hbuf[cur] + aoff[kk]);

        // lin(h_{s-1}) on ALL waves (in-register feedback), 2 chains
        floatx4 al0 = floatx4{0,0,0,0}, al1 = floatx4{0,0,0,0};
        floatx4 acc[2][2];
        #pragma unroll
        for (int i = 0; i < 2; ++i) {
            acc[i][0] = bia4[i];
            acc[i][1] = floatx4{0, 0, 0, 0};
        }
        #pragma unroll
        for (int kk = 0; kk < 8; ++kk) {
            if (kk & 1) al1 = __builtin_amdgcn_mfma_f32_16x16x32_f16(wlf[kk], a[kk], al1, 0, 0, 0);
            else        al0 = __builtin_amdgcn_mfma_f32_16x16x32_f16(wlf[kk], a[kk], al0, 0, 0, 0);
            acc[0][kk & 1] = __builtin_amdgcn_mfma_f32_16x16x32_f16(wf[0][kk], a[kk], acc[0][kk & 1], 0, 0, 0);
            acc[1][kk & 1] = __builtin_amdgcn_mfma_f32_16x16x32_f16(wf[1][kk], a[kk], acc[1][kk & 1], 0, 0, 0);
        }
        if (w == 0 && lg == 0)                         // output record only
            obuf2[(t_out >> 5) & 1][t_out & 31][ln15] = al0[0] + al1[0];

        const float xm = al0[0] + al1[0] + blin;       // per-lane feedback, row ln15
        #pragma unroll
        for (int i = 0; i < 2; ++i) {
            const floatx4 av = acc[i][0] + acc[i][1];
            half4 hv;
            #pragma unroll
            for (int r = 0; r < 4; ++r)
                hv[r] = (_Float16)tanh_fast(__builtin_fmaf(xm, wih4[i][r], av[r]));
            *(half4*)(hbuf[cur ^ 1] + woff2[i]) = hv;
        }
        __syncthreads();
        cur ^= 1;
    }

    // final out t = 2175 = lin(h_final): one more lin tile on wave 0
    if (w == 0) {
        half8 a[8];
        #pragma unroll
        for (int kk = 0; kk < 8; ++kk)
            a[kk] = *(const half8*)(hbuf[cur] + aoff[kk]);
        floatx4 al0 = floatx4{0,0,0,0}, al1 = floatx4{0,0,0,0};
        #pragma unroll
        for (int kk = 0; kk < 8; ++kk) {
            if (kk & 1) al1 = __builtin_amdgcn_mfma_f32_16x16x32_f16(wlf[kk], a[kk], al1, 0, 0, 0);
            else        al0 = __builtin_amdgcn_mfma_f32_16x16x32_f16(wlf[kk], a[kk], al0, 0, 0, 0);
        }
        if (lg == 0) obuf2[1][31][ln15] = al0[0] + al1[0];
    }
    __syncthreads();
    {   // final flush t = 2144..2175 (parity 1); 2144..2174 written in-loop,
        // 2175 just above
        const int rr = tid >> 5, tt = tid & 31;
        out[(size_t)(b0 + rr) * T_TOT + 2144 + tt] = obuf2[1][tt][rr] + blin;
    }
}

extern "C" void kernel_launch(void* const* d_in, const int* in_sizes, int n_in,
                              void* d_out, int out_size, void* d_ws, size_t ws_size,
                              hipStream_t stream) {
    const float* x     = (const float*)d_in[0];
    const float* W_ih  = (const float*)d_in[1];
    const float* b_ih  = (const float*)d_in[2];
    const float* W_hh  = (const float*)d_in[3];
    const float* b_hh  = (const float*)d_in[4];
    const float* W_lin = (const float*)d_in[5];
    const float* b_lin = (const float*)d_in[6];
    float* out = (float*)d_out;
    rnn_seq_kernel<<<B_TOT / ROWS, 512, 0, stream>>>(x, W_ih, b_ih, W_hh, b_hh, W_lin, b_lin, out);
}

// Round 14
// 1573.059 us; speedup vs baseline: 1.1838x; 1.0148x over previous
//
#include <hip/hip_runtime.h>
#include <hip/hip_bf16.h>

typedef _Float16 half8 __attribute__((ext_vector_type(8)));
typedef _Float16 half4 __attribute__((ext_vector_type(4)));
typedef float    floatx4 __attribute__((ext_vector_type(4)));

#define B_TOT 4096
#define L_SEQ 2048
#define H_DIM 256
#define FUT   128
#define T_TOT (L_SEQ + FUT)   /* 2176 */
#define ROWS  16              /* batch rows per block */
#define CHUNK 128             /* x prefetch chunk (steps) */

// tanh(p) = 1 - 2/(e^{2p}+1); exp2 over/underflow saturate to exact +-1.
__device__ __forceinline__ float tanh_fast(float p) {
    float e = __builtin_amdgcn_exp2f(p * 2.885390082f);     // e^(2p)
    return __builtin_fmaf(-2.0f, __builtin_amdgcn_rcpf(e + 1.0f), 1.0f);
}

// BEST-KNOWN (R8, 1574 us): 8 waves x 2 N-tiles, swapped-operand MFMA
// C = W_tile(A) @ h^T(B), XOR-swizzled fp16 h double-buffer, post-barrier
// wave-0 lin (a[] regs survive the barrier; overlaps other waves' next-step
// LDS reads), W_lin in A-rows {0,4,8,12} so al[0] is valid in every lane
// group -> future-phase feedback in-register, 1 barrier/step; LDS out-ring
// with coalesced 32-step flushes.
// Tested-and-rejected levers (kept out): fewer waves (R4), forced
// co-residency (R5/R6), spin-flag sync (R9), K-order skew (R10/R11),
// s_setprio (R11), pre-barrier distributed lin (R12), per-step x register
// prefetch (R13).  The kernel is latency-bound on the serial step chain;
// all saturable-pipe counters sit far below their ceilings by necessity.
__global__ __launch_bounds__(512, 2) void rnn_seq_kernel(
    const float* __restrict__ x,      // [B, L]
    const float* __restrict__ W_ih,   // [H]
    const float* __restrict__ b_ih,   // [H]
    const float* __restrict__ W_hh,   // [H, H]
    const float* __restrict__ b_hh,   // [H]
    const float* __restrict__ W_lin,  // [H]
    const float* __restrict__ b_lin,  // [1]
    float* __restrict__ out)          // [B, T_TOT]
{
    __shared__ __align__(16) unsigned char hbuf[2][ROWS * H_DIM * 2]; // fp16 dbuf
    __shared__ __align__(16) float xbuf[CHUNK * 17];                  // [t_local][row]
    __shared__ __align__(16) float obuf2[2][32][17];                  // out ring

    const int tid  = threadIdx.x;
    const int l    = tid & 63;
    const int w    = tid >> 6;       // wave 0..7
    const int ln15 = l & 15;
    const int lg   = l >> 4;         // 0..3
    const int b0   = blockIdx.x * ROWS;

    // ---- loop-invariant register state ----
    half8 wf[2][8];                   // W_hh A-frags: 2 N-tiles per wave
    #pragma unroll
    for (int i = 0; i < 2; ++i) {
        const int n = (2 * w + i) * 16 + ln15;
        #pragma unroll
        for (int kk = 0; kk < 8; ++kk) {
            const float* p = W_hh + n * H_DIM + kk * 32 + lg * 8;
            half8 v;
            #pragma unroll
            for (int j = 0; j < 8; ++j) v[j] = (_Float16)p[j];
            wf[i][kk] = v;
        }
    }
    // W_lin A-frag in rows 0,4,8,12 -> C rows 0,4,8,12 all = lin(h):
    // al[0] (reg 0) is valid at every lane group lg.
    half8 wlf[8];
    #pragma unroll
    for (int kk = 0; kk < 8; ++kk) {
        const int kbase = kk * 32 + lg * 8;
        half8 v;
        #pragma unroll
        for (int j = 0; j < 8; ++j)
            v[j] = ((ln15 & 3) == 0) ? (_Float16)W_lin[kbase + j] : (_Float16)0.0f;
        wlf[kk] = v;
    }
    floatx4 wih4[2], bia4[2];
    #pragma unroll
    for (int i = 0; i < 2; ++i) {
        const int n0 = (2 * w + i) * 16 + lg * 4;
        #pragma unroll
        for (int r = 0; r < 4; ++r) {
            wih4[i][r] = W_ih[n0 + r];
            bia4[i][r] = b_ih[n0 + r] + b_hh[n0 + r];
        }
    }
    const float blin = b_lin[0];

    // LDS byte offsets (XOR swizzle bits 4-6 keyed by row&7)
    int aoff[8];
    #pragma unroll
    for (int kk = 0; kk < 8; ++kk)
        aoff[kk] = (ln15 * 512 + kk * 64 + lg * 16) ^ ((ln15 & 7) << 4);
    int woff2[2];
    #pragma unroll
    for (int i = 0; i < 2; ++i)
        woff2[i] = (ln15 * 512 + (2 * w + i) * 32 + lg * 8) ^ ((ln15 & 7) << 4);

    *(floatx4*)(hbuf[0] + tid * 16) = floatx4{0.f, 0.f, 0.f, 0.f};  // h0 = 0
    __syncthreads();

    int cur = 0;

    // ============================ main phase ============================
    for (int s = 1; s <= L_SEQ; ++s) {
        const int t_out = s - 2;

        // flush completed 32-block [t_out-34, t_out-3]: newest entry was
        // written >=2 barriers ago (post-barrier lin writes need the margin)
        if (t_out >= 34 && (t_out & 31) == 2) {
            const int tb = t_out - 34, par = (tb >> 5) & 1;
            const int rr = tid >> 5, tt = tid & 31;
            out[(size_t)(b0 + rr) * T_TOT + tb + tt] = obuf2[par][tt][rr] + blin;
        }
        if (((s - 1) & (CHUNK - 1)) == 0) {           // x chunk prefetch
            #pragma unroll
            for (int jj = 0; jj < 4; ++jj) {
                const int idx = jj * 512 + tid;
                const int rr = idx >> 7, tl = idx & 127;
                xbuf[tl * 17 + rr] = x[(size_t)(b0 + rr) * L_SEQ + (s - 1) + tl];
            }
            __syncthreads();
        }

        half8 a[8];                                    // B-frags of h_{s-1}
        #pragma unroll
        for (int kk = 0; kk < 8; ++kk)
            a[kk] = *(const half8*)(hbuf[cur] + aoff[kk]);
        const float xm = xbuf[((s - 1) & (CHUNK - 1)) * 17 + ln15];

        // 2 chains per tile; chain0 init = fma(x, W_ih, bias)
        floatx4 acc[2][2];
        #pragma unroll
        for (int i = 0; i < 2; ++i) {
            #pragma unroll
            for (int r = 0; r < 4; ++r)
                acc[i][0][r] = __builtin_fmaf(xm, wih4[i][r], bia4[i][r]);
            acc[i][1] = floatx4{0, 0, 0, 0};
        }
        #pragma unroll
        for (int kk = 0; kk < 8; ++kk) {
            acc[0][kk & 1] = __builtin_amdgcn_mfma_f32_16x16x32_f16(wf[0][kk], a[kk], acc[0][kk & 1], 0, 0, 0);
            acc[1][kk & 1] = __builtin_amdgcn_mfma_f32_16x16x32_f16(wf[1][kk], a[kk], acc[1][kk & 1], 0, 0, 0);
        }
        // tanh + packed b64 h-write
        #pragma unroll
        for (int i = 0; i < 2; ++i) {
            const floatx4 av = acc[i][0] + acc[i][1];
            half4 hv;
            #pragma unroll
            for (int r = 0; r < 4; ++r) hv[r] = (_Float16)tanh_fast(av[r]);
            *(half4*)(hbuf[cur ^ 1] + woff2[i]) = hv;
        }
        __syncthreads();

        // lin AFTER the barrier (wave 0 only; a[] regs still hold h_{s-1}):
        // overlaps the other waves' next-step LDS reads.
        if (w == 0 && s >= 2) {
            floatx4 al0 = floatx4{0,0,0,0}, al1 = floatx4{0,0,0,0};
            #pragma unroll
            for (int kk = 0; kk < 8; ++kk) {
                if (kk & 1) al1 = __builtin_amdgcn_mfma_f32_16x16x32_f16(wlf[kk], a[kk], al1, 0, 0, 0);
                else        al0 = __builtin_amdgcn_mfma_f32_16x16x32_f16(wlf[kk], a[kk], al0, 0, 0, 0);
            }
            if (lg == 0)
                obuf2[(t_out >> 5) & 1][t_out & 31][ln15] = al0[0] + al1[0];
        }
        cur ^= 1;
    }

    // ============================ future phase ============================
    // feedback is in-register (al[0] valid in every lane group): 1 barrier/step
    for (int s = L_SEQ + 1; s <= T_TOT; ++s) {
        const int t_out = s - 2;
        if ((t_out & 31) == 2) {                       // ring flush (same margin)
            const int tb = t_out - 34, par = (tb >> 5) & 1;
            const int rr = tid >> 5, tt = tid & 31;
            out[(size_t)(b0 + rr) * T_TOT + tb + tt] = obuf2[par][tt][rr] + blin;
        }
        half8 a[8];
        #pragma unroll
        for (int kk = 0; kk < 8; ++kk)
            a[kk] = *(const half8*)(hbuf[cur] + aoff[kk]);

        // lin(h_{s-1}) on ALL waves (in-register feedback), 2 chains
        floatx4 al0 = floatx4{0,0,0,0}, al1 = floatx4{0,0,0,0};
        floatx4 acc[2][2];
        #pragma unroll
        for (int i = 0; i < 2; ++i) {
            acc[i][0] = bia4[i];
            acc[i][1] = floatx4{0, 0, 0, 0};
        }
        #pragma unroll
        for (int kk = 0; kk < 8; ++kk) {
            if (kk & 1) al1 = __builtin_amdgcn_mfma_f32_16x16x32_f16(wlf[kk], a[kk], al1, 0, 0, 0);
            else        al0 = __builtin_amdgcn_mfma_f32_16x16x32_f16(wlf[kk], a[kk], al0, 0, 0, 0);
            acc[0][kk & 1] = __builtin_amdgcn_mfma_f32_16x16x32_f16(wf[0][kk], a[kk], acc[0][kk & 1], 0, 0, 0);
            acc[1][kk & 1] = __builtin_amdgcn_mfma_f32_16x16x32_f16(wf[1][kk], a[kk], acc[1][kk & 1], 0, 0, 0);
        }
        if (w == 0 && lg == 0)                         // output record only
            obuf2[(t_out >> 5) & 1][t_out & 31][ln15] = al0[0] + al1[0];

        const float xm = al0[0] + al1[0] + blin;       // per-lane feedback, row ln15
        #pragma unroll
        for (int i = 0; i < 2; ++i) {
            const floatx4 av = acc[i][0] + acc[i][1];
            half4 hv;
            #pragma unroll
            for (int r = 0; r < 4; ++r)
                hv[r] = (_Float16)tanh_fast(__builtin_fmaf(xm, wih4[i][r], av[r]));
            *(half4*)(hbuf[cur ^ 1] + woff2[i]) = hv;
        }
        __syncthreads();
        cur ^= 1;
    }

    // final out t = 2175 = lin(h_final): one more lin tile on wave 0
    if (w == 0) {
        half8 a[8];
        #pragma unroll
        for (int kk = 0; kk < 8; ++kk)
            a[kk] = *(const half8*)(hbuf[cur] + aoff[kk]);
        floatx4 al0 = floatx4{0,0,0,0}, al1 = floatx4{0,0,0,0};
        #pragma unroll
        for (int kk = 0; kk < 8; ++kk) {
            if (kk & 1) al1 = __builtin_amdgcn_mfma_f32_16x16x32_f16(wlf[kk], a[kk], al1, 0, 0, 0);
            else        al0 = __builtin_amdgcn_mfma_f32_16x16x32_f16(wlf[kk], a[kk], al0, 0, 0, 0);
        }
        if (lg == 0) obuf2[1][31][ln15] = al0[0] + al1[0];
    }
    __syncthreads();
    {   // final flush t = 2144..2175 (parity 1); 2144..2174 written in-loop,
        // 2175 just above
        const int rr = tid >> 5, tt = tid & 31;
        out[(size_t)(b0 + rr) * T_TOT + 2144 + tt] = obuf2[1][tt][rr] + blin;
    }
}

extern "C" void kernel_launch(void* const* d_in, const int* in_sizes, int n_in,
                              void* d_out, int out_size, void* d_ws, size_t ws_size,
                              hipStream_t stream) {
    const float* x     = (const float*)d_in[0];
    const float* W_ih  = (const float*)d_in[1];
    const float* b_ih  = (const float*)d_in[2];
    const float* W_hh  = (const float*)d_in[3];
    const float* b_hh  = (const float*)d_in[4];
    const float* W_lin = (const float*)d_in[5];
    const float* b_lin = (const float*)d_in[6];
    float* out = (float*)d_out;
    rnn_seq_kernel<<<B_TOT / ROWS, 512, 0, stream>>>(x, W_ih, b_ih, W_hh, b_hh, W_lin, b_lin, out);
}